// Round 6
// baseline (770.311 us; speedup 1.0000x reference)
//
#include <hip/hip_runtime.h>

#define DIM 256
#define NEMB 8192
#define NQ 32768
#define OUT_Q_ELEMS 8388608   // 8*4096*256
#define NSEG 2
#define SEG_CODES 4096
#define CAP_H 16              // per (row, seg, wn-quarter) candidate capacity
#define MARGIN 1.0f

typedef __attribute__((ext_vector_type(8))) short short8;
typedef __attribute__((ext_vector_type(4))) float f32x4;
typedef unsigned int u32_as1 __attribute__((address_space(1)));
typedef unsigned int u32_as3 __attribute__((address_space(3)));

// fp32 -> bf16 round-to-nearest-even
__device__ __forceinline__ unsigned short f2bf(float f) {
    unsigned u = __float_as_uint(f);
    u += 0x7FFFu + ((u >> 16) & 1u);
    return (unsigned short)(u >> 16);
}
// async global->LDS, 16B per lane (dest = wave-uniform base + lane*16)
__device__ __forceinline__ void gll16(const void* g, void* l) {
    __builtin_amdgcn_global_load_lds((const u32_as1*)g, (u32_as3*)l, 16, 0, 0);
}

// The EXACT proven-passing metric: fp32 k-ascending single-accumulator fmaf
// chain, dist = ed[c] - 2*(double)dot. 2-deep pipelined 64B loads.
__device__ __forceinline__ double chain_dist(const float* __restrict__ ep,
                                             const float* __restrict__ xs,
                                             double edc) {
    float acc = 0.0f;
    float4 e0 = *(const float4*)(ep);
    float4 e1 = *(const float4*)(ep + 4);
    float4 e2 = *(const float4*)(ep + 8);
    float4 e3 = *(const float4*)(ep + 12);
#pragma unroll
    for (int kk = 0; kk < 15; ++kk) {
        const int k = kk * 16;
        float4 n0 = *(const float4*)(ep + k + 16);
        float4 n1 = *(const float4*)(ep + k + 20);
        float4 n2 = *(const float4*)(ep + k + 24);
        float4 n3 = *(const float4*)(ep + k + 28);
        float4 x0 = *(const float4*)(xs + k);
        float4 x1 = *(const float4*)(xs + k + 4);
        float4 x2 = *(const float4*)(xs + k + 8);
        float4 x3 = *(const float4*)(xs + k + 12);
        acc = fmaf(x0.x, e0.x, acc); acc = fmaf(x0.y, e0.y, acc);
        acc = fmaf(x0.z, e0.z, acc); acc = fmaf(x0.w, e0.w, acc);
        acc = fmaf(x1.x, e1.x, acc); acc = fmaf(x1.y, e1.y, acc);
        acc = fmaf(x1.z, e1.z, acc); acc = fmaf(x1.w, e1.w, acc);
        acc = fmaf(x2.x, e2.x, acc); acc = fmaf(x2.y, e2.y, acc);
        acc = fmaf(x2.z, e2.z, acc); acc = fmaf(x2.w, e2.w, acc);
        acc = fmaf(x3.x, e3.x, acc); acc = fmaf(x3.y, e3.y, acc);
        acc = fmaf(x3.z, e3.z, acc); acc = fmaf(x3.w, e3.w, acc);
        e0 = n0; e1 = n1; e2 = n2; e3 = n3;
    }
    {
        const int k = 240;
        float4 x0 = *(const float4*)(xs + k);
        float4 x1 = *(const float4*)(xs + k + 4);
        float4 x2 = *(const float4*)(xs + k + 8);
        float4 x3 = *(const float4*)(xs + k + 12);
        acc = fmaf(x0.x, e0.x, acc); acc = fmaf(x0.y, e0.y, acc);
        acc = fmaf(x0.z, e0.z, acc); acc = fmaf(x0.w, e0.w, acc);
        acc = fmaf(x1.x, e1.x, acc); acc = fmaf(x1.y, e1.y, acc);
        acc = fmaf(x1.z, e1.z, acc); acc = fmaf(x1.w, e1.w, acc);
        acc = fmaf(x2.x, e2.x, acc); acc = fmaf(x2.y, e2.y, acc);
        acc = fmaf(x2.z, e2.z, acc); acc = fmaf(x2.w, e2.w, acc);
        acc = fmaf(x3.x, e3.x, acc); acc = fmaf(x3.y, e3.y, acc);
        acc = fmaf(x3.z, e3.z, acc); acc = fmaf(x3.w, e3.w, acc);
    }
    return edc - 2.0 * (double)acc;
}

// ---------------------------------------------------------------------------
// Merged prep kernel, block ranges:
//   [0,512)      zero cnt2 (512 KB)
//   [512,544)    enorm (fp64 + fp32 codebook norms)
//   [544,1056)   ebt   (embed^T via LDS-tiled transpose)
//   [1056,5152)  xc    (X -> bf16 LDS-image tiles)
//   [5152,6176)  ec    (E -> bf16 LDS-image tiles, transposed)
// ---------------------------------------------------------------------------
__global__ void prep_kernel(const float* __restrict__ input,
                            const float* __restrict__ embed,
                            unsigned short* __restrict__ cnt2,
                            double* __restrict__ ed,
                            float* __restrict__ ef, float* __restrict__ ebt,
                            unsigned short* __restrict__ Xc,
                            unsigned short* __restrict__ Ec) {
    __shared__ float t[64][65];
    const int b = blockIdx.x;
    if (b < 512) {
        ((int*)cnt2)[b * 256 + threadIdx.x] = 0;
    } else if (b < 544) {
        int j = (b - 512) * 256 + threadIdx.x;
        double s = 0.0;
        for (int d = 0; d < DIM; ++d) {
            double v = (double)embed[(size_t)d * NEMB + j];
            s += v * v;
        }
        ed[j] = s;
        ef[j] = (float)s;
    } else if (b < 1056) {
        const int bb = b - 544;
        const int bx = bb & 127, by = bb >> 7;
        const int tx = threadIdx.x & 63, ty = threadIdx.x >> 6;
#pragma unroll
        for (int i = 0; i < 16; ++i) {
            int d = by * 64 + ty * 16 + i;
            t[ty * 16 + i][tx] = embed[(size_t)d * NEMB + bx * 64 + tx];
        }
        __syncthreads();
#pragma unroll
        for (int i = 0; i < 16; ++i) {
            int c = bx * 64 + ty * 16 + i;
            ebt[(size_t)c * DIM + by * 64 + tx] = t[tx][ty * 16 + i];
        }
    } else if (b < 5152) {
        int tid = (b - 1056) * 256 + threadIdx.x;  // NQ*32 units
        int q = tid >> 5, kcc = tid & 31;
        const float* p = input + (size_t)q * DIM + kcc * 8;
        float4 a = *(const float4*)p;
        float4 bv = *(const float4*)(p + 4);
        int mb = q >> 7, mrow = q & 127, kc = kcc >> 3, c = kcc & 7;
        short8 v;
        v[0] = (short)f2bf(a.x);  v[1] = (short)f2bf(a.y);
        v[2] = (short)f2bf(a.z);  v[3] = (short)f2bf(a.w);
        v[4] = (short)f2bf(bv.x); v[5] = (short)f2bf(bv.y);
        v[6] = (short)f2bf(bv.z); v[7] = (short)f2bf(bv.w);
        *(short8*)(Xc + (size_t)((((mb * 4 + kc) * 8) + c) * 128 + mrow) * 8) = v;
    } else {
        int tid = (b - 5152) * 256 + threadIdx.x;  // NEMB*32 units, n fast
        int n = tid & (NEMB - 1), kcc = tid >> 13;
        int nb = n >> 7, nrow = n & 127, kc = kcc >> 3, c = kcc & 7;
        short8 v;
#pragma unroll
        for (int j = 0; j < 8; ++j)
            v[j] = (short)f2bf(embed[(size_t)(kc * 64 + c * 8 + j) * NEMB + n]);
        *(short8*)(Ec + (size_t)((((nb * 4 + kc) * 8) + c) * 128 + nrow) * 8) = v;
    }
}

// ---------------------------------------------------------------------------
// MFMA argmin v7: ONE 16-wave block per CU, 160 KB LDS (the full pool).
//
// R5 post-mortem: v6 (64x64 tiles, 2 waves/SIMD) had NOTHING saturated
// (Mfma 21%, VALU 26%, LDS ~31%) -> latency-bound: at 8 waves/CU every
// drain+barrier idles the SIMDs. v2's edge was its 4 waves/SIMD, not its
// pipeline. The unique config with 64x64 tiles (32.8 FLOP/LDS-byte) AND
// 16 waves/CU AND A-resident (R2-R4: A cannot live in VGPRs nor restream):
//   - 1024 threads, 16 waves, 4M x 4N; wave tile 64x64 (acc[4][4]).
//   - A = 256 rows x 256 K = 128 KB LDS-resident (two mb-strips).
//   - B double-buffered BK=32 chunks covering 256 cols (2 x 16 KB).
//     160 KB total; grid 256 = 1 block/CU, one clean round.
//   - Per chunk: issue next 16 KB stage (1 gll16/thread), 8 ds_read_b128,
//     16 MFMA, [epilogue at tile end], vmcnt(0)+s_barrier. CU-level chunk
//     compute ~1500 cy >> load latency -> drain covered WITHIN the block.
//   - 128 chunks, 16 epilogues (both halved vs v6).
//   - launch_bounds(1024,4): VGPR cap 128 (natural 112 measured in v6).
//
// Epilogue semantics unchanged (s-space, exact per-tile cross-lane
// threshold, single-ballot fast path, ballot-prefix slots); list geometry
// = v4's PROVEN (row, seg, wn-quarter) x CAP 16, ushort cnt2.
// ---------------------------------------------------------------------------
__global__ __launch_bounds__(1024, 4) void mfma_argmin_kernel(
    const unsigned short* __restrict__ Xc, const unsigned short* __restrict__ Ec,
    const float* __restrict__ ef, unsigned short* __restrict__ cnt2,
    unsigned short* __restrict__ cand) {
    __shared__ unsigned short As[65536];    // 128 KB: 256 rows x full K
    __shared__ unsigned short Bs[2][8192];  // 2 x 16 KB: BK=32, 256 cols

    const int tid = threadIdx.x;
    const int w = tid >> 6, l = tid & 63;
    const int wm = w >> 2, wn = w & 3;        // 4M x 4N wave tiling
    const int l15 = l & 15, q4 = l >> 4;
    const int mbp = blockIdx.x & 127;         // 256-row pair of mb strips
    const int seg = blockIdx.x >> 7;

    const unsigned short* xt = Xc + (size_t)mbp * 65536;
    const unsigned short* Eseg = Ec + ((size_t)seg << 20);  // seg*32 nb-tiles

    const int sh = tid >> 9, su = tid & 511;  // B-stage: half, idx-in-half

    // ---- stage the whole A pair-strip once (8 gll16/thread = 128 KB)
#pragma unroll
    for (int s = 0; s < 8; ++s)
        gll16(xt + s * 8192 + tid * 8, &As[s * 8192 + tid * 8]);
    // ---- stage B chunk 0 (16 KB: nb-halves st*2, st*2+1 of supertile 0)
    gll16(Eseg + (size_t)sh * 32768 + su * 8, &Bs[0][sh * 4096 + su * 8]);
    asm volatile("s_waitcnt vmcnt(0)" ::: "memory");
    asm volatile("s_barrier" ::: "memory");

    float rmax[4][4];   // cross-lane running max of s (per row-group), exact
    int   rcnt[4][4];   // per row-group candidate count (uniform over l15)
#pragma unroll
    for (int i = 0; i < 4; ++i)
#pragma unroll
        for (int r = 0; r < 4; ++r) { rmax[i][r] = -1e30f; rcnt[i][r] = 0; }

    // A-strip addressing constants for this wave
    const int astrip = (wm >> 1) * 32768;
    const int arow = (wm & 1) * 64;

    for (int st = 0; st < 16; ++st) {        // 256-col supertiles
        const int col0 = seg * 4096 + st * 256 + wn * 64 + l15;
        float enh[4];
#pragma unroll
        for (int j = 0; j < 4; ++j) enh[j] = 0.5f * ef[col0 + 16 * j];

        f32x4 acc[4][4];
#pragma unroll
        for (int i = 0; i < 4; ++i)
#pragma unroll
            for (int j = 0; j < 4; ++j) acc[i][j] = (f32x4){0.f, 0.f, 0.f, 0.f};

#pragma unroll
        for (int c8 = 0; c8 < 8; ++c8) {
            // ---- issue next chunk's stage (1 gll16/thread, 16 KB)
            const int nc = st * 8 + c8 + 1;  // linear chunk id 1..128
            if (nc < 128) {
                const int nst = nc >> 3, nc8 = nc & 7;
                gll16(Eseg + (size_t)(nst * 2 + sh) * 32768 + nc8 * 4096 +
                          su * 8,
                      &Bs[nc & 1][sh * 4096 + su * 8]);
            }

            // ---- compute chunk c8: af from resident A, bf from dbuf
            short8 af[4], bf[4];
#pragma unroll
            for (int i = 0; i < 4; ++i)
                af[i] = *(const short8*)&As[astrip +
                    ((c8 * 4 + q4) * 128 + arow + i * 16 + l15) * 8];
#pragma unroll
            for (int j = 0; j < 4; ++j)
                bf[j] = *(const short8*)&Bs[c8 & 1][(wn >> 1) * 4096 +
                    (q4 * 128 + (wn & 1) * 64 + j * 16 + l15) * 8];

            __builtin_amdgcn_s_setprio(1);
#pragma unroll
            for (int i = 0; i < 4; ++i)
#pragma unroll
                for (int j = 0; j < 4; ++j)
                    acc[i][j] = __builtin_amdgcn_mfma_f32_16x16x32_bf16(
                        af[i], bf[j], acc[i][j], 0, 0, 0);
            __builtin_amdgcn_s_setprio(0);

            if (c8 == 7) {
                // ---- epilogue (next tile's chunk 0 in flight underneath):
                // s-space, exact per-tile threshold, ballot collection
#pragma unroll
                for (int i = 0; i < 4; ++i)
#pragma unroll
                    for (int r = 0; r < 4; ++r) {
                        const float s0 = acc[i][0][r] - enh[0];
                        const float s1 = acc[i][1][r] - enh[1];
                        const float s2 = acc[i][2][r] - enh[2];
                        const float s3 = acc[i][3][r] - enh[3];
                        float M = fmaxf(fmaxf(fmaxf(s0, s1), fmaxf(s2, s3)),
                                        rmax[i][r]);
#pragma unroll
                        for (int step = 1; step < 16; step <<= 1)
                            M = fmaxf(M, __shfl_xor(M, step, 64));  // row max
                        rmax[i][r] = M;
                        const float tau = M - 0.5f * MARGIN;
                        const float sm = fmaxf(fmaxf(s0, s1), fmaxf(s2, s3));
                        const unsigned long long bb = __ballot(sm > tau);
                        const unsigned g = (unsigned)(bb >> (q4 * 16)) & 0xFFFFu;
                        if (g) {  // rare slow path: per-j allocation
                            int base = rcnt[i][r];
                            const int row256 = wm * 64 + i * 16 + q4 * 4 + r;
                            const int qrow = mbp * 256 + row256;
                            const size_t cb =
                                ((size_t)(qrow * NSEG + seg) * 4 + wn) * CAP_H;
                            const float sj[4] = {s0, s1, s2, s3};
#pragma unroll
                            for (int j = 0; j < 4; ++j) {
                                const bool cdd = sj[j] > tau;
                                const unsigned long long bj = __ballot(cdd);
                                const unsigned gj =
                                    (unsigned)(bj >> (q4 * 16)) & 0xFFFFu;
                                if (cdd) {
                                    int slot =
                                        base + __popc(gj & ((1u << l15) - 1u));
                                    if (slot < CAP_H)
                                        cand[cb + slot] =
                                            (unsigned short)(col0 + 16 * j);
                                }
                                base += __popc(gj);
                            }
                            rcnt[i][r] = base;
                        }
                    }
            }
            // ---- drain: next chunk landed (issued ~1500 CU-cycles ago)
            asm volatile("s_waitcnt vmcnt(0)" ::: "memory");
            asm volatile("s_barrier" ::: "memory");
        }
    }
    // ---- store per-(row,seg,quarter) counts (uniform over l15)
    if (l15 == 0) {
#pragma unroll
        for (int i = 0; i < 4; ++i)
#pragma unroll
            for (int r = 0; r < 4; ++r) {
                const int row256 = wm * 64 + i * 16 + q4 * 4 + r;
                const int qrow = mbp * 256 + row256;
                cnt2[(qrow * NSEG + seg) * 4 + wn] =
                    (unsigned short)rcnt[i][r];
            }
    }
}

// ---------------------------------------------------------------------------
// Rescore (v4's PROVEN 8-list version): merge the 8 per-(seg,quarter) lists;
// bit-exact proven-passing metric, smallest-index tie-break; bounded per-seg
// scan on overflow. Fused with quantize gather + fp64 diff partial.
// ---------------------------------------------------------------------------
__global__ __launch_bounds__(256) void rescore_kernel(
    const float* __restrict__ input, const float* __restrict__ ebt,
    const double* __restrict__ ed, const unsigned short* __restrict__ cnt2,
    const unsigned short* __restrict__ cand, float* __restrict__ out_q,
    float* __restrict__ out_idx, double* __restrict__ partials) {
    __shared__ float Xs[4][DIM];
    const int w = threadIdx.x >> 6, l = threadIdx.x & 63;
    const int q = blockIdx.x * 4 + w;
    const float* xs = Xs[w];

    float4 xf = *(const float4*)(input + (size_t)q * DIM + 4 * l);
    *(float4*)&Xs[w][4 * l] = xf;
    __syncthreads();

    int m[8];
    bool segscan[NSEG];
#pragma unroll
    for (int s2 = 0; s2 < NSEG; ++s2) segscan[s2] = false;
#pragma unroll
    for (int li = 0; li < 8; ++li) {
        int ns = cnt2[(q * NSEG + (li >> 2)) * 4 + (li & 3)];
        if (ns > CAP_H) segscan[li >> 2] = true;
        m[li] = ns;
    }
#pragma unroll
    for (int li = 0; li < 8; ++li)
        if (segscan[li >> 2]) m[li] = 0;  // seg scan supersedes its quarters

    int tot = 0;
#pragma unroll
    for (int li = 0; li < 8; ++li) tot += m[li];

    double bd = 1e300;
    int bc = 0x7FFFFFFF;

    for (int base = 0; base < tot; base += 64) {
        const int idx = base + l;
        if (idx < tot) {
            int rem = idx, li = 0;
#pragma unroll
            for (int li2 = 0; li2 < 7; ++li2)
                if (rem >= m[li]) { rem -= m[li]; ++li; }
            const int c = cand[((size_t)(q * NSEG + (li >> 2)) * 4 + (li & 3))
                               * CAP_H + rem];
            double d = chain_dist(ebt + (size_t)c * DIM, xs, ed[c]);
            if (d < bd || (d == bd && c < bc)) { bd = d; bc = c; }
        }
    }
#pragma unroll
    for (int s2 = 0; s2 < NSEG; ++s2) {  // bounded fallback on overflow
        if (segscan[s2]) {
            for (int c = s2 * SEG_CODES + l; c < (s2 + 1) * SEG_CODES; c += 64) {
                double d = chain_dist(ebt + (size_t)c * DIM, xs, ed[c]);
                if (d < bd || (d == bd && c < bc)) { bd = d; bc = c; }
            }
        }
    }
#pragma unroll
    for (int off = 1; off < 64; off <<= 1) {
        double od = __shfl_xor(bd, off, 64);
        int oc = __shfl_xor(bc, off, 64);
        if (od < bd || (od == bd && oc < bc)) { bd = od; bc = oc; }
    }

    float4 e4 = *(const float4*)(ebt + (size_t)bc * DIM + 4 * l);
    *(float4*)(out_q + (size_t)q * DIM + 4 * l) = e4;
    float d0 = e4.x - xf.x, d1 = e4.y - xf.y;
    float d2 = e4.z - xf.z, d3 = e4.w - xf.w;
    double dd = (double)d0 * d0 + (double)d1 * d1 +
                (double)d2 * d2 + (double)d3 * d3;
#pragma unroll
    for (int off = 1; off < 64; off <<= 1) dd += __shfl_xor(dd, off, 64);
    if (l == 0) {
        out_idx[q] = (float)bc;
        partials[q] = dd;
    }
}

// ---------------------------------------------------------------------------
// reduce partials -> mean -> diff
// ---------------------------------------------------------------------------
__global__ void diff_kernel(const double* __restrict__ partials,
                            float* __restrict__ out_diff) {
    const int t = threadIdx.x;
    double s = 0.0;
    for (int i = t; i < NQ; i += 256) s += partials[i];
#pragma unroll
    for (int off = 32; off >= 1; off >>= 1) s += __shfl_down(s, off, 64);
    __shared__ double red[4];
    if ((t & 63) == 0) red[t >> 6] = s;
    __syncthreads();
    if (t == 0)
        out_diff[0] = (float)((red[0] + red[1] + red[2] + red[3]) /
                              (double)OUT_Q_ELEMS);
}

extern "C" void kernel_launch(void* const* d_in, const int* in_sizes, int n_in,
                              void* d_out, int out_size, void* d_ws,
                              size_t ws_size, hipStream_t stream) {
    const float* input = (const float*)d_in[0];  // [8,4096,256] fp32
    const float* embed = (const float*)d_in[1];  // [256,8192]  fp32

    float* out_q    = (float*)d_out;             // quantize
    float* out_diff = out_q + OUT_Q_ELEMS;       // diff scalar
    float* out_idx  = out_diff + 1;              // embed_ind (as float)

    char* p = (char*)d_ws;
    unsigned short* Ec  = (unsigned short*)(p);                 //  4 MB
    unsigned short* Xc  = (unsigned short*)(p + 4194304);       // 16 MB
    float*          ebt = (float*)(p + 20971520);               //  8 MB
    double*         ed  = (double*)(p + 29360128);              // 64 KB
    float*          ef  = (float*)(p + 29425664);               // 32 KB
    unsigned short* cnt2 = (unsigned short*)(p + 29458432);     // 512 KB
    double*         partials = (double*)(p + 29982720);         // 256 KB
    unsigned short* cand = (unsigned short*)(p + 30244864);     //  8 MB

    hipLaunchKernelGGL(prep_kernel, dim3(6176), dim3(256), 0, stream,
                       input, embed, cnt2, ed, ef, ebt, Xc, Ec);
    hipLaunchKernelGGL(mfma_argmin_kernel, dim3((NQ / 256) * NSEG), dim3(1024),
                       0, stream, Xc, Ec, ef, cnt2, cand);
    hipLaunchKernelGGL(rescore_kernel, dim3(NQ / 4), dim3(256), 0, stream,
                       input, ebt, ed, cnt2, cand, out_q, out_idx, partials);
    hipLaunchKernelGGL(diff_kernel, dim3(1), dim3(256), 0, stream,
                       partials, out_diff);
}

// Round 7
// 657.071 us; speedup vs baseline: 1.1723x; 1.1723x over previous
//
#include <hip/hip_runtime.h>

#define DIM 256
#define NEMB 8192
#define NQ 32768
#define OUT_Q_ELEMS 8388608   // 8*4096*256
#define NSEG 2
#define SEG_CODES 4096
#define CAP_H 16              // per (row, seg, wn-quarter) candidate capacity
#define MARGIN 1.0f

typedef __attribute__((ext_vector_type(8))) short short8;
typedef __attribute__((ext_vector_type(4))) float f32x4;
typedef unsigned int u32_as1 __attribute__((address_space(1)));
typedef unsigned int u32_as3 __attribute__((address_space(3)));

// fp32 -> bf16 round-to-nearest-even
__device__ __forceinline__ unsigned short f2bf(float f) {
    unsigned u = __float_as_uint(f);
    u += 0x7FFFu + ((u >> 16) & 1u);
    return (unsigned short)(u >> 16);
}
// async global->LDS, 16B per lane (dest = wave-uniform base + lane*16)
__device__ __forceinline__ void gll16(const void* g, void* l) {
    __builtin_amdgcn_global_load_lds((const u32_as1*)g, (u32_as3*)l, 16, 0, 0);
}

// The EXACT proven-passing metric: fp32 k-ascending single-accumulator fmaf
// chain, dist = ed[c] - 2*(double)dot. 2-deep pipelined 64B loads.
__device__ __forceinline__ double chain_dist(const float* __restrict__ ep,
                                             const float* __restrict__ xs,
                                             double edc) {
    float acc = 0.0f;
    float4 e0 = *(const float4*)(ep);
    float4 e1 = *(const float4*)(ep + 4);
    float4 e2 = *(const float4*)(ep + 8);
    float4 e3 = *(const float4*)(ep + 12);
#pragma unroll
    for (int kk = 0; kk < 15; ++kk) {
        const int k = kk * 16;
        float4 n0 = *(const float4*)(ep + k + 16);
        float4 n1 = *(const float4*)(ep + k + 20);
        float4 n2 = *(const float4*)(ep + k + 24);
        float4 n3 = *(const float4*)(ep + k + 28);
        float4 x0 = *(const float4*)(xs + k);
        float4 x1 = *(const float4*)(xs + k + 4);
        float4 x2 = *(const float4*)(xs + k + 8);
        float4 x3 = *(const float4*)(xs + k + 12);
        acc = fmaf(x0.x, e0.x, acc); acc = fmaf(x0.y, e0.y, acc);
        acc = fmaf(x0.z, e0.z, acc); acc = fmaf(x0.w, e0.w, acc);
        acc = fmaf(x1.x, e1.x, acc); acc = fmaf(x1.y, e1.y, acc);
        acc = fmaf(x1.z, e1.z, acc); acc = fmaf(x1.w, e1.w, acc);
        acc = fmaf(x2.x, e2.x, acc); acc = fmaf(x2.y, e2.y, acc);
        acc = fmaf(x2.z, e2.z, acc); acc = fmaf(x2.w, e2.w, acc);
        acc = fmaf(x3.x, e3.x, acc); acc = fmaf(x3.y, e3.y, acc);
        acc = fmaf(x3.z, e3.z, acc); acc = fmaf(x3.w, e3.w, acc);
        e0 = n0; e1 = n1; e2 = n2; e3 = n3;
    }
    {
        const int k = 240;
        float4 x0 = *(const float4*)(xs + k);
        float4 x1 = *(const float4*)(xs + k + 4);
        float4 x2 = *(const float4*)(xs + k + 8);
        float4 x3 = *(const float4*)(xs + k + 12);
        acc = fmaf(x0.x, e0.x, acc); acc = fmaf(x0.y, e0.y, acc);
        acc = fmaf(x0.z, e0.z, acc); acc = fmaf(x0.w, e0.w, acc);
        acc = fmaf(x1.x, e1.x, acc); acc = fmaf(x1.y, e1.y, acc);
        acc = fmaf(x1.z, e1.z, acc); acc = fmaf(x1.w, e1.w, acc);
        acc = fmaf(x2.x, e2.x, acc); acc = fmaf(x2.y, e2.y, acc);
        acc = fmaf(x2.z, e2.z, acc); acc = fmaf(x2.w, e2.w, acc);
        acc = fmaf(x3.x, e3.x, acc); acc = fmaf(x3.y, e3.y, acc);
        acc = fmaf(x3.z, e3.z, acc); acc = fmaf(x3.w, e3.w, acc);
    }
    return edc - 2.0 * (double)acc;
}

// ---------------------------------------------------------------------------
// Merged prep kernel, block ranges:
//   [0,512)      zero cnt2 (512 KB)
//   [512,544)    enorm (fp64 + fp32 codebook norms)
//   [544,1056)   ebt   (embed^T via LDS-tiled transpose)
//   [1056,5152)  xc    (X -> bf16 LDS-image tiles)
//   [5152,6176)  ec    (E -> bf16 LDS-image tiles, transposed)
// ---------------------------------------------------------------------------
__global__ void prep_kernel(const float* __restrict__ input,
                            const float* __restrict__ embed,
                            unsigned short* __restrict__ cnt2,
                            double* __restrict__ ed,
                            float* __restrict__ ef, float* __restrict__ ebt,
                            unsigned short* __restrict__ Xc,
                            unsigned short* __restrict__ Ec) {
    __shared__ float t[64][65];
    const int b = blockIdx.x;
    if (b < 512) {
        ((int*)cnt2)[b * 256 + threadIdx.x] = 0;
    } else if (b < 544) {
        int j = (b - 512) * 256 + threadIdx.x;
        double s = 0.0;
        for (int d = 0; d < DIM; ++d) {
            double v = (double)embed[(size_t)d * NEMB + j];
            s += v * v;
        }
        ed[j] = s;
        ef[j] = (float)s;
    } else if (b < 1056) {
        const int bb = b - 544;
        const int bx = bb & 127, by = bb >> 7;
        const int tx = threadIdx.x & 63, ty = threadIdx.x >> 6;
#pragma unroll
        for (int i = 0; i < 16; ++i) {
            int d = by * 64 + ty * 16 + i;
            t[ty * 16 + i][tx] = embed[(size_t)d * NEMB + bx * 64 + tx];
        }
        __syncthreads();
#pragma unroll
        for (int i = 0; i < 16; ++i) {
            int c = bx * 64 + ty * 16 + i;
            ebt[(size_t)c * DIM + by * 64 + tx] = t[tx][ty * 16 + i];
        }
    } else if (b < 5152) {
        int tid = (b - 1056) * 256 + threadIdx.x;  // NQ*32 units
        int q = tid >> 5, kcc = tid & 31;
        const float* p = input + (size_t)q * DIM + kcc * 8;
        float4 a = *(const float4*)p;
        float4 bv = *(const float4*)(p + 4);
        int mb = q >> 7, mrow = q & 127, kc = kcc >> 3, c = kcc & 7;
        short8 v;
        v[0] = (short)f2bf(a.x);  v[1] = (short)f2bf(a.y);
        v[2] = (short)f2bf(a.z);  v[3] = (short)f2bf(a.w);
        v[4] = (short)f2bf(bv.x); v[5] = (short)f2bf(bv.y);
        v[6] = (short)f2bf(bv.z); v[7] = (short)f2bf(bv.w);
        *(short8*)(Xc + (size_t)((((mb * 4 + kc) * 8) + c) * 128 + mrow) * 8) = v;
    } else {
        int tid = (b - 5152) * 256 + threadIdx.x;  // NEMB*32 units, n fast
        int n = tid & (NEMB - 1), kcc = tid >> 13;
        int nb = n >> 7, nrow = n & 127, kc = kcc >> 3, c = kcc & 7;
        short8 v;
#pragma unroll
        for (int j = 0; j < 8; ++j)
            v[j] = (short)f2bf(embed[(size_t)(kc * 64 + c * 8 + j) * NEMB + n]);
        *(short8*)(Ec + (size_t)((((nb * 4 + kc) * 8) + c) * 128 + nrow) * 8) = v;
    }
}

// ---------------------------------------------------------------------------
// MFMA argmin v8: 64x64 wave tiles at 16 waves/CU, A-resident, 80 KB exactly.
//
// Constraint set (all HW-measured this session):
//   - 64x64 wave tile -> 32.8 FLOP/LDS-byte (LDS floor 82us/CU vs v2's 123).
//   - A must be LDS-resident (R2-R4: VGPR-A and restreamed-A both spill/thrash).
//   - 16 waves/CU needed (v2 vs v6: TLP is the only working stall cover).
//   - VGPR cap law: cap = 256/min_waves arg. (.,4)->64 caused v4/v7 spills;
//     (512,2)->128, and v6 measured 112 for this exact register structure.
// Unique solution: 512 thr (8 waves, 2M x 4N), As 64 KB + ONE 16 KB B buffer
// (256 cols x K=32) = 80 KB -> 2 blocks/CU. Single-buffer B: per chunk
//   { barrier; stage 16KB (2 gll16/thr); af ds_reads (from As, safe);
//     vmcnt(0); barrier; bf reads; 16 MFMA }
// Stage exposure ~200cy/chunk is covered by the co-resident block + 8 waves.
// Barrier count = 2 x 128 = v2's 256. Grid 512 = one clean round.
//
// Epilogue: v4's PROVEN 256-col supertile geometry ((row,seg,quarter) lists,
// CAP 16, ushort cnt2) with v6's PROVEN register rmax/rcnt. Same exact
// s-space threshold math, single-ballot fast path, ballot-prefix slots.
// ---------------------------------------------------------------------------
__global__ __launch_bounds__(512, 2) void mfma_argmin_kernel(
    const unsigned short* __restrict__ Xc, const unsigned short* __restrict__ Ec,
    const float* __restrict__ ef, unsigned short* __restrict__ cnt2,
    unsigned short* __restrict__ cand) {
    __shared__ unsigned short As[32768];  // 64 KB: full-K A strip (resident)
    __shared__ unsigned short Bs[8192];   // 16 KB: one (st, kc) chunk, 256 cols

    const int tid = threadIdx.x;
    const int w = tid >> 6, l = tid & 63;
    const int wm = w >> 2, wn = w & 3;        // 2M x 4N wave tiling
    const int l15 = l & 15, q4 = l >> 4;
    const int mb = blockIdx.x & 255;
    const int seg = blockIdx.x >> 8;

    const unsigned short* xt = Xc + (size_t)mb * 32768;
    const unsigned short* Eseg = Ec + ((size_t)seg << 20);  // seg*32 nb-tiles

    // ---- stage the whole A strip once (8 rounds x 512 thr x 16B = 64 KB)
#pragma unroll
    for (int s = 0; s < 8; ++s)
        gll16(xt + s * 4096 + tid * 8, &As[s * 4096 + tid * 8]);
    asm volatile("s_waitcnt vmcnt(0)" ::: "memory");
    asm volatile("s_barrier" ::: "memory");

    float rmax[4][4];   // cross-lane running max of s (per row-group), exact
    int   rcnt[4][4];   // per row-group candidate count (uniform over l15)
#pragma unroll
    for (int i = 0; i < 4; ++i)
#pragma unroll
        for (int r = 0; r < 4; ++r) { rmax[i][r] = -1e30f; rcnt[i][r] = 0; }

    for (int st = 0; st < 16; ++st) {        // 256-col supertiles
        const int col0 = seg * 4096 + st * 256 + wn * 64 + l15;
        float enh[4];
#pragma unroll
        for (int j = 0; j < 4; ++j) enh[j] = 0.5f * ef[col0 + 16 * j];

        f32x4 acc[4][4];
#pragma unroll
        for (int i = 0; i < 4; ++i)
#pragma unroll
            for (int j = 0; j < 4; ++j) acc[i][j] = (f32x4){0.f, 0.f, 0.f, 0.f};

#pragma unroll
        for (int c8 = 0; c8 < 8; ++c8) {
            // ---- Bs free to overwrite (all waves past last chunk's reads)
            asm volatile("s_barrier" ::: "memory");
            // ---- stage current chunk (st, c8): both 128-col pieces, 16 KB
#pragma unroll
            for (int p = 0; p < 2; ++p)
                gll16(Eseg + (size_t)(st * 2 + p) * 32768 + c8 * 4096 + tid * 8,
                      &Bs[p * 4096 + tid * 8]);
            // ---- af from resident As (independent of the in-flight stage)
            short8 af[4];
#pragma unroll
            for (int i = 0; i < 4; ++i)
                af[i] = *(const short8*)&As[
                    ((c8 * 4 + q4) * 128 + wm * 64 + i * 16 + l15) * 8];
            // ---- chunk landed
            asm volatile("s_waitcnt vmcnt(0)" ::: "memory");
            asm volatile("s_barrier" ::: "memory");

            short8 bf[4];
#pragma unroll
            for (int j = 0; j < 4; ++j)
                bf[j] = *(const short8*)&Bs[(wn >> 1) * 4096 +
                    (q4 * 128 + (wn & 1) * 64 + j * 16 + l15) * 8];

            __builtin_amdgcn_s_setprio(1);
#pragma unroll
            for (int i = 0; i < 4; ++i)
#pragma unroll
                for (int j = 0; j < 4; ++j)
                    acc[i][j] = __builtin_amdgcn_mfma_f32_16x16x32_bf16(
                        af[i], bf[j], acc[i][j], 0, 0, 0);
            __builtin_amdgcn_s_setprio(0);
        }

        // ---- per-supertile epilogue: s-space, exact per-tile cross-lane
        // threshold, single-ballot fast path, ballot-prefix slot allocation
#pragma unroll
        for (int i = 0; i < 4; ++i)
#pragma unroll
            for (int r = 0; r < 4; ++r) {
                const float s0 = acc[i][0][r] - enh[0];
                const float s1 = acc[i][1][r] - enh[1];
                const float s2 = acc[i][2][r] - enh[2];
                const float s3 = acc[i][3][r] - enh[3];
                float M = fmaxf(fmaxf(fmaxf(s0, s1), fmaxf(s2, s3)),
                                rmax[i][r]);
#pragma unroll
                for (int step = 1; step < 16; step <<= 1)
                    M = fmaxf(M, __shfl_xor(M, step, 64));  // exact row max
                rmax[i][r] = M;
                const float tau = M - 0.5f * MARGIN;
                const float sm = fmaxf(fmaxf(s0, s1), fmaxf(s2, s3));
                const unsigned long long bb = __ballot(sm > tau);
                const unsigned g = (unsigned)(bb >> (q4 * 16)) & 0xFFFFu;
                if (g) {  // rare slow path: per-j allocation
                    int base = rcnt[i][r];
                    const int row128 = wm * 64 + i * 16 + q4 * 4 + r;
                    const int qrow = mb * 128 + row128;
                    const size_t cb =
                        ((size_t)(qrow * NSEG + seg) * 4 + wn) * CAP_H;
                    const float sj[4] = {s0, s1, s2, s3};
#pragma unroll
                    for (int j = 0; j < 4; ++j) {
                        const bool cdd = sj[j] > tau;
                        const unsigned long long bj = __ballot(cdd);
                        const unsigned gj =
                            (unsigned)(bj >> (q4 * 16)) & 0xFFFFu;
                        if (cdd) {
                            int slot = base + __popc(gj & ((1u << l15) - 1u));
                            if (slot < CAP_H)
                                cand[cb + slot] =
                                    (unsigned short)(col0 + 16 * j);
                        }
                        base += __popc(gj);
                    }
                    rcnt[i][r] = base;
                }
            }
    }
    // ---- store per-(row,seg,quarter) counts (uniform over l15)
    if (l15 == 0) {
#pragma unroll
        for (int i = 0; i < 4; ++i)
#pragma unroll
            for (int r = 0; r < 4; ++r) {
                const int row128 = wm * 64 + i * 16 + q4 * 4 + r;
                const int qrow = mb * 128 + row128;
                cnt2[(qrow * NSEG + seg) * 4 + wn] =
                    (unsigned short)rcnt[i][r];
            }
    }
}

// ---------------------------------------------------------------------------
// Rescore (v4's PROVEN 8-list version): merge the 8 per-(seg,quarter) lists;
// bit-exact proven-passing metric, smallest-index tie-break; bounded per-seg
// scan on overflow. Fused with quantize gather + fp64 diff partial.
// ---------------------------------------------------------------------------
__global__ __launch_bounds__(256) void rescore_kernel(
    const float* __restrict__ input, const float* __restrict__ ebt,
    const double* __restrict__ ed, const unsigned short* __restrict__ cnt2,
    const unsigned short* __restrict__ cand, float* __restrict__ out_q,
    float* __restrict__ out_idx, double* __restrict__ partials) {
    __shared__ float Xs[4][DIM];
    const int w = threadIdx.x >> 6, l = threadIdx.x & 63;
    const int q = blockIdx.x * 4 + w;
    const float* xs = Xs[w];

    float4 xf = *(const float4*)(input + (size_t)q * DIM + 4 * l);
    *(float4*)&Xs[w][4 * l] = xf;
    __syncthreads();

    int m[8];
    bool segscan[NSEG];
#pragma unroll
    for (int s2 = 0; s2 < NSEG; ++s2) segscan[s2] = false;
#pragma unroll
    for (int li = 0; li < 8; ++li) {
        int ns = cnt2[(q * NSEG + (li >> 2)) * 4 + (li & 3)];
        if (ns > CAP_H) segscan[li >> 2] = true;
        m[li] = ns;
    }
#pragma unroll
    for (int li = 0; li < 8; ++li)
        if (segscan[li >> 2]) m[li] = 0;  // seg scan supersedes its quarters

    int tot = 0;
#pragma unroll
    for (int li = 0; li < 8; ++li) tot += m[li];

    double bd = 1e300;
    int bc = 0x7FFFFFFF;

    for (int base = 0; base < tot; base += 64) {
        const int idx = base + l;
        if (idx < tot) {
            int rem = idx, li = 0;
#pragma unroll
            for (int li2 = 0; li2 < 7; ++li2)
                if (rem >= m[li]) { rem -= m[li]; ++li; }
            const int c = cand[((size_t)(q * NSEG + (li >> 2)) * 4 + (li & 3))
                               * CAP_H + rem];
            double d = chain_dist(ebt + (size_t)c * DIM, xs, ed[c]);
            if (d < bd || (d == bd && c < bc)) { bd = d; bc = c; }
        }
    }
#pragma unroll
    for (int s2 = 0; s2 < NSEG; ++s2) {  // bounded fallback on overflow
        if (segscan[s2]) {
            for (int c = s2 * SEG_CODES + l; c < (s2 + 1) * SEG_CODES; c += 64) {
                double d = chain_dist(ebt + (size_t)c * DIM, xs, ed[c]);
                if (d < bd || (d == bd && c < bc)) { bd = d; bc = c; }
            }
        }
    }
#pragma unroll
    for (int off = 1; off < 64; off <<= 1) {
        double od = __shfl_xor(bd, off, 64);
        int oc = __shfl_xor(bc, off, 64);
        if (od < bd || (od == bd && oc < bc)) { bd = od; bc = oc; }
    }

    float4 e4 = *(const float4*)(ebt + (size_t)bc * DIM + 4 * l);
    *(float4*)(out_q + (size_t)q * DIM + 4 * l) = e4;
    float d0 = e4.x - xf.x, d1 = e4.y - xf.y;
    float d2 = e4.z - xf.z, d3 = e4.w - xf.w;
    double dd = (double)d0 * d0 + (double)d1 * d1 +
                (double)d2 * d2 + (double)d3 * d3;
#pragma unroll
    for (int off = 1; off < 64; off <<= 1) dd += __shfl_xor(dd, off, 64);
    if (l == 0) {
        out_idx[q] = (float)bc;
        partials[q] = dd;
    }
}

// ---------------------------------------------------------------------------
// reduce partials -> mean -> diff
// ---------------------------------------------------------------------------
__global__ void diff_kernel(const double* __restrict__ partials,
                            float* __restrict__ out_diff) {
    const int t = threadIdx.x;
    double s = 0.0;
    for (int i = t; i < NQ; i += 256) s += partials[i];
#pragma unroll
    for (int off = 32; off >= 1; off >>= 1) s += __shfl_down(s, off, 64);
    __shared__ double red[4];
    if ((t & 63) == 0) red[t >> 6] = s;
    __syncthreads();
    if (t == 0)
        out_diff[0] = (float)((red[0] + red[1] + red[2] + red[3]) /
                              (double)OUT_Q_ELEMS);
}

extern "C" void kernel_launch(void* const* d_in, const int* in_sizes, int n_in,
                              void* d_out, int out_size, void* d_ws,
                              size_t ws_size, hipStream_t stream) {
    const float* input = (const float*)d_in[0];  // [8,4096,256] fp32
    const float* embed = (const float*)d_in[1];  // [256,8192]  fp32

    float* out_q    = (float*)d_out;             // quantize
    float* out_diff = out_q + OUT_Q_ELEMS;       // diff scalar
    float* out_idx  = out_diff + 1;              // embed_ind (as float)

    char* p = (char*)d_ws;
    unsigned short* Ec  = (unsigned short*)(p);                 //  4 MB
    unsigned short* Xc  = (unsigned short*)(p + 4194304);       // 16 MB
    float*          ebt = (float*)(p + 20971520);               //  8 MB
    double*         ed  = (double*)(p + 29360128);              // 64 KB
    float*          ef  = (float*)(p + 29425664);               // 32 KB
    unsigned short* cnt2 = (unsigned short*)(p + 29458432);     // 512 KB
    double*         partials = (double*)(p + 29982720);         // 256 KB
    unsigned short* cand = (unsigned short*)(p + 30244864);     //  8 MB

    hipLaunchKernelGGL(prep_kernel, dim3(6176), dim3(256), 0, stream,
                       input, embed, cnt2, ed, ef, ebt, Xc, Ec);
    hipLaunchKernelGGL(mfma_argmin_kernel, dim3((NQ / 128) * NSEG), dim3(512),
                       0, stream, Xc, Ec, ef, cnt2, cand);
    hipLaunchKernelGGL(rescore_kernel, dim3(NQ / 4), dim3(256), 0, stream,
                       input, ebt, ed, cnt2, cand, out_q, out_idx, partials);
    hipLaunchKernelGGL(diff_kernel, dim3(1), dim3(256), 0, stream,
                       partials, out_diff);
}

// Round 8
// 493.930 us; speedup vs baseline: 1.5596x; 1.3303x over previous
//
#include <hip/hip_runtime.h>

#define DIM 256
#define NEMB 8192
#define NQ 32768
#define OUT_Q_ELEMS 8388608   // 8*4096*256
#define NSEG 2
#define SEG_CODES 4096
#define CAP_H 32              // per (row, seg, wn-half) candidate capacity
#define MARGIN 1.0f

typedef __attribute__((ext_vector_type(8))) short short8;
typedef __attribute__((ext_vector_type(4))) float f32x4;
typedef unsigned int u32_as1 __attribute__((address_space(1)));
typedef unsigned int u32_as3 __attribute__((address_space(3)));

// fp32 -> bf16 round-to-nearest-even
__device__ __forceinline__ unsigned short f2bf(float f) {
    unsigned u = __float_as_uint(f);
    u += 0x7FFFu + ((u >> 16) & 1u);
    return (unsigned short)(u >> 16);
}
// async global->LDS, 16B per lane (dest = wave-uniform base + lane*16)
__device__ __forceinline__ void gll16(const void* g, void* l) {
    __builtin_amdgcn_global_load_lds((const u32_as1*)g, (u32_as3*)l, 16, 0, 0);
}

// The EXACT proven-passing metric: fp32 k-ascending single-accumulator fmaf
// chain, dist = ed[c] - 2*(double)dot. 2-deep pipelined 64B loads.
__device__ __forceinline__ double chain_dist(const float* __restrict__ ep,
                                             const float* __restrict__ xs,
                                             double edc) {
    float acc = 0.0f;
    float4 e0 = *(const float4*)(ep);
    float4 e1 = *(const float4*)(ep + 4);
    float4 e2 = *(const float4*)(ep + 8);
    float4 e3 = *(const float4*)(ep + 12);
#pragma unroll
    for (int kk = 0; kk < 15; ++kk) {
        const int k = kk * 16;
        float4 n0 = *(const float4*)(ep + k + 16);
        float4 n1 = *(const float4*)(ep + k + 20);
        float4 n2 = *(const float4*)(ep + k + 24);
        float4 n3 = *(const float4*)(ep + k + 28);
        float4 x0 = *(const float4*)(xs + k);
        float4 x1 = *(const float4*)(xs + k + 4);
        float4 x2 = *(const float4*)(xs + k + 8);
        float4 x3 = *(const float4*)(xs + k + 12);
        acc = fmaf(x0.x, e0.x, acc); acc = fmaf(x0.y, e0.y, acc);
        acc = fmaf(x0.z, e0.z, acc); acc = fmaf(x0.w, e0.w, acc);
        acc = fmaf(x1.x, e1.x, acc); acc = fmaf(x1.y, e1.y, acc);
        acc = fmaf(x1.z, e1.z, acc); acc = fmaf(x1.w, e1.w, acc);
        acc = fmaf(x2.x, e2.x, acc); acc = fmaf(x2.y, e2.y, acc);
        acc = fmaf(x2.z, e2.z, acc); acc = fmaf(x2.w, e2.w, acc);
        acc = fmaf(x3.x, e3.x, acc); acc = fmaf(x3.y, e3.y, acc);
        acc = fmaf(x3.z, e3.z, acc); acc = fmaf(x3.w, e3.w, acc);
        e0 = n0; e1 = n1; e2 = n2; e3 = n3;
    }
    {
        const int k = 240;
        float4 x0 = *(const float4*)(xs + k);
        float4 x1 = *(const float4*)(xs + k + 4);
        float4 x2 = *(const float4*)(xs + k + 8);
        float4 x3 = *(const float4*)(xs + k + 12);
        acc = fmaf(x0.x, e0.x, acc); acc = fmaf(x0.y, e0.y, acc);
        acc = fmaf(x0.z, e0.z, acc); acc = fmaf(x0.w, e0.w, acc);
        acc = fmaf(x1.x, e1.x, acc); acc = fmaf(x1.y, e1.y, acc);
        acc = fmaf(x1.z, e1.z, acc); acc = fmaf(x1.w, e1.w, acc);
        acc = fmaf(x2.x, e2.x, acc); acc = fmaf(x2.y, e2.y, acc);
        acc = fmaf(x2.z, e2.z, acc); acc = fmaf(x2.w, e2.w, acc);
        acc = fmaf(x3.x, e3.x, acc); acc = fmaf(x3.y, e3.y, acc);
        acc = fmaf(x3.z, e3.z, acc); acc = fmaf(x3.w, e3.w, acc);
    }
    return edc - 2.0 * (double)acc;
}

// ---------------------------------------------------------------------------
// Merged prep kernel, block ranges:
//   [0,512)      zero cnt2 (131072 ints)
//   [512,544)    enorm (fp64 + fp32 codebook norms); b==512 also zeroes pacc
//   [544,1056)   ebt   (embed^T via LDS-tiled transpose)
//   [1056,5152)  xc    (X -> bf16 LDS-image tiles)
//   [5152,6176)  ec    (E -> bf16 LDS-image tiles, transposed)
// ---------------------------------------------------------------------------
__global__ void prep_kernel(const float* __restrict__ input,
                            const float* __restrict__ embed,
                            int* __restrict__ cnt2, double* __restrict__ ed,
                            float* __restrict__ ef, float* __restrict__ ebt,
                            unsigned short* __restrict__ Xc,
                            unsigned short* __restrict__ Ec,
                            double* __restrict__ pacc) {
    __shared__ float t[64][65];
    const int b = blockIdx.x;
    if (b < 512) {
        cnt2[b * 256 + threadIdx.x] = 0;
    } else if (b < 544) {
        if (b == 512 && threadIdx.x < 64) pacc[threadIdx.x] = 0.0;
        int j = (b - 512) * 256 + threadIdx.x;
        double s = 0.0;
        for (int d = 0; d < DIM; ++d) {
            double v = (double)embed[(size_t)d * NEMB + j];
            s += v * v;
        }
        ed[j] = s;
        ef[j] = (float)s;
    } else if (b < 1056) {
        const int bb = b - 544;
        const int bx = bb & 127, by = bb >> 7;
        const int tx = threadIdx.x & 63, ty = threadIdx.x >> 6;
#pragma unroll
        for (int i = 0; i < 16; ++i) {
            int d = by * 64 + ty * 16 + i;
            t[ty * 16 + i][tx] = embed[(size_t)d * NEMB + bx * 64 + tx];
        }
        __syncthreads();
#pragma unroll
        for (int i = 0; i < 16; ++i) {
            int c = bx * 64 + ty * 16 + i;
            ebt[(size_t)c * DIM + by * 64 + tx] = t[tx][ty * 16 + i];
        }
    } else if (b < 5152) {
        int tid = (b - 1056) * 256 + threadIdx.x;  // NQ*32 units
        int q = tid >> 5, kcc = tid & 31;
        const float* p = input + (size_t)q * DIM + kcc * 8;
        float4 a = *(const float4*)p;
        float4 bv = *(const float4*)(p + 4);
        int mb = q >> 7, mrow = q & 127, kc = kcc >> 3, c = kcc & 7;
        short8 v;
        v[0] = (short)f2bf(a.x);  v[1] = (short)f2bf(a.y);
        v[2] = (short)f2bf(a.z);  v[3] = (short)f2bf(a.w);
        v[4] = (short)f2bf(bv.x); v[5] = (short)f2bf(bv.y);
        v[6] = (short)f2bf(bv.z); v[7] = (short)f2bf(bv.w);
        *(short8*)(Xc + (size_t)((((mb * 4 + kc) * 8) + c) * 128 + mrow) * 8) = v;
    } else {
        int tid = (b - 5152) * 256 + threadIdx.x;  // NEMB*32 units, n fast
        int n = tid & (NEMB - 1), kcc = tid >> 13;
        int nb = n >> 7, nrow = n & 127, kc = kcc >> 3, c = kcc & 7;
        short8 v;
#pragma unroll
        for (int j = 0; j < 8; ++j)
            v[j] = (short)f2bf(embed[(size_t)(kc * 64 + c * 8 + j) * NEMB + n]);
        *(short8*)(Ec + (size_t)((((nb * 4 + kc) * 8) + c) * 128 + nrow) * 8) = v;
    }
}

// ---------------------------------------------------------------------------
// MFMA argmin (R1 champion, 225 us, VERBATIM): 8-wave (512-thread) blocks,
// 4M x 2N wave tiling (wave = 32 rows x 64 cols), A-strip (64 KB full-K)
// LDS-resident, B double-buffered in BK=32 chunks (2 x 8 KB) -> 80 KB,
// 2 blocks/CU. Unified regs = 64 VGPR + 32 AGPR = 96 <= 128 -> 16 waves/CU
// (the binding constraint discovered R2-R7: 64-AGPR tiles cap at 8 waves/CU
// and always lose; this geometry is the constrained optimum).
// ---------------------------------------------------------------------------
__global__ __launch_bounds__(512, 4) void mfma_argmin_kernel(
    const unsigned short* __restrict__ Xc, const unsigned short* __restrict__ Ec,
    const float* __restrict__ ef, int* __restrict__ cnt2,
    unsigned short* __restrict__ cand) {
    __shared__ unsigned short As[32768];   // 64 KB: full-K A strip
    __shared__ unsigned short Bs[2][4096]; // 2 x 8 KB: BK=32 double buffer

    const int tid = threadIdx.x;
    const int w = tid >> 6, l = tid & 63;
    const int wm = w >> 1, wn = w & 1;        // 4M x 2N wave tiling
    const int l15 = l & 15, q4 = l >> 4;
    const int mb = blockIdx.x & 255;
    const int seg = blockIdx.x >> 8;

    const unsigned short* xt = Xc + (size_t)mb * 32768;
    const unsigned short* Eseg = Ec + ((size_t)seg << 20);  // seg*32 tiles

    // ---- stage the whole A strip (8 gll16/wave) + B chunk 0, then drain once
#pragma unroll
    for (int s = 0; s < 8; ++s) {
        const int t = w * 8 + s;
        gll16(xt + t * 512 + l * 8, &As[t * 512 + l * 8]);
    }
    gll16(Eseg + w * 512 + l * 8, &Bs[0][w * 512 + l * 8]);
    asm volatile("s_waitcnt vmcnt(0)" ::: "memory");
    asm volatile("s_barrier" ::: "memory");

    float rmax[2][4];   // cross-lane running max of s (per row-group), exact
    int   rcnt[2][4];   // per row-group candidate count (uniform over l15)
#pragma unroll
    for (int i = 0; i < 2; ++i)
#pragma unroll
        for (int r = 0; r < 4; ++r) { rmax[i][r] = -1e30f; rcnt[i][r] = 0; }

    for (int t16 = 0; t16 < 32; ++t16) {
        const int nb = seg * 32 + t16;
        const int col0 = nb * 128 + wn * 64 + l15;
        float enh[4];
#pragma unroll
        for (int j = 0; j < 4; ++j) enh[j] = 0.5f * ef[col0 + 16 * j];

        f32x4 acc[2][4];
#pragma unroll
        for (int i = 0; i < 2; ++i)
#pragma unroll
            for (int j = 0; j < 4; ++j) acc[i][j] = (f32x4){0.f, 0.f, 0.f, 0.f};

#pragma unroll
        for (int c8 = 0; c8 < 8; ++c8) {
            // ---- issue next chunk's stage (1 gll16/wave), double-buffered
            const int nc = t16 * 8 + c8 + 1;  // linear chunk id 1..256
            if (nc < 256)
                gll16(Eseg + ((size_t)nc << 12) + w * 512 + l * 8,
                      &Bs[nc & 1][w * 512 + l * 8]);

            const int kc = c8 >> 1, h = c8 & 1;
            short8 af[2], bf[4];
#pragma unroll
            for (int i = 0; i < 2; ++i)
                af[i] = *(const short8*)&As[kc * 8192 +
                    ((h * 4 + q4) * 128 + wm * 32 + i * 16 + l15) * 8];
#pragma unroll
            for (int j = 0; j < 4; ++j)
                bf[j] = *(const short8*)&Bs[h][
                    (q4 * 128 + wn * 64 + j * 16 + l15) * 8];

            __builtin_amdgcn_s_setprio(1);
#pragma unroll
            for (int i = 0; i < 2; ++i)
#pragma unroll
                for (int j = 0; j < 4; ++j)
                    acc[i][j] = __builtin_amdgcn_mfma_f32_16x16x32_bf16(
                        af[i], bf[j], acc[i][j], 0, 0, 0);
            __builtin_amdgcn_s_setprio(0);

            if (c8 == 7) {
                // ---- epilogue (next tile's chunk 0 is in flight underneath):
                // s-space, exact per-tile threshold, ballot collection
#pragma unroll
                for (int i = 0; i < 2; ++i)
#pragma unroll
                    for (int r = 0; r < 4; ++r) {
                        const float s0 = acc[i][0][r] - enh[0];
                        const float s1 = acc[i][1][r] - enh[1];
                        const float s2 = acc[i][2][r] - enh[2];
                        const float s3 = acc[i][3][r] - enh[3];
                        float M = fmaxf(fmaxf(fmaxf(s0, s1), fmaxf(s2, s3)),
                                        rmax[i][r]);
#pragma unroll
                        for (int step = 1; step < 16; step <<= 1)
                            M = fmaxf(M, __shfl_xor(M, step, 64));  // row max
                        rmax[i][r] = M;
                        const float tau = M - 0.5f * MARGIN;
                        const float sm = fmaxf(fmaxf(s0, s1), fmaxf(s2, s3));
                        const unsigned long long bb = __ballot(sm > tau);
                        const unsigned g = (unsigned)(bb >> (q4 * 16)) & 0xFFFFu;
                        if (g) {  // rare slow path: per-j allocation
                            int base = rcnt[i][r];
                            const int row128 = wm * 32 + i * 16 + q4 * 4 + r;
                            const size_t cb =
                                ((size_t)((mb * 128 + row128) * NSEG + seg) * 2 +
                                 wn) * CAP_H;
                            const float sj[4] = {s0, s1, s2, s3};
#pragma unroll
                            for (int j = 0; j < 4; ++j) {
                                const bool cdd = sj[j] > tau;
                                const unsigned long long bj = __ballot(cdd);
                                const unsigned gj =
                                    (unsigned)(bj >> (q4 * 16)) & 0xFFFFu;
                                if (cdd) {
                                    int slot =
                                        base + __popc(gj & ((1u << l15) - 1u));
                                    if (slot < CAP_H)
                                        cand[cb + slot] =
                                            (unsigned short)(col0 + 16 * j);
                                }
                                base += __popc(gj);
                            }
                            rcnt[i][r] = base;
                        }
                    }
            }
            // ---- counted drain: next chunk landed; keep loads flowing
            asm volatile("s_waitcnt vmcnt(0)" ::: "memory");
            asm volatile("s_barrier" ::: "memory");
        }
    }
    // ---- store per-(row,seg,half) counts (uniform over l15)
    if (l15 == 0) {
#pragma unroll
        for (int i = 0; i < 2; ++i)
#pragma unroll
            for (int r = 0; r < 4; ++r) {
                const int row128 = wm * 32 + i * 16 + q4 * 4 + r;
                cnt2[((mb * 128 + row128) * NSEG + seg) * 2 + wn] = rcnt[i][r];
            }
    }
}

// ---------------------------------------------------------------------------
// Rescore: merge the 4 per-(seg,half) lists; bit-exact proven-passing metric,
// smallest-index tie-break; bounded per-seg scan on overflow (P ~ 1e-6).
// Fused with quantize gather + fp64 diff partial. One wave per query.
// NEW: per-block fp64 reduce + atomicAdd into 64 contention-spread slots
// (replaces the 256 KB partials round-trip + grid(1) diff reduction).
// ---------------------------------------------------------------------------
__global__ __launch_bounds__(256) void rescore_kernel(
    const float* __restrict__ input, const float* __restrict__ ebt,
    const double* __restrict__ ed, const int* __restrict__ cnt2,
    const unsigned short* __restrict__ cand, float* __restrict__ out_q,
    float* __restrict__ out_idx, double* __restrict__ pacc) {
    __shared__ float Xs[4][DIM];
    __shared__ double dred[4];
    const int w = threadIdx.x >> 6, l = threadIdx.x & 63;
    const int q = blockIdx.x * 4 + w;
    const float* xs = Xs[w];

    float4 xf = *(const float4*)(input + (size_t)q * DIM + 4 * l);
    *(float4*)&Xs[w][4 * l] = xf;
    __syncthreads();

    int m[4];
    bool segscan[NSEG];
#pragma unroll
    for (int s2 = 0; s2 < NSEG; ++s2) segscan[s2] = false;
#pragma unroll
    for (int li = 0; li < 4; ++li) {
        int ns = cnt2[(q * NSEG + (li >> 1)) * 2 + (li & 1)];
        if (ns > CAP_H) segscan[li >> 1] = true;
        m[li] = ns;
    }
#pragma unroll
    for (int li = 0; li < 4; ++li)
        if (segscan[li >> 1]) m[li] = 0;  // seg scan supersedes its halves

    int tot = 0;
#pragma unroll
    for (int li = 0; li < 4; ++li) tot += m[li];

    double bd = 1e300;
    int bc = 0x7FFFFFFF;

    for (int base = 0; base < tot; base += 64) {
        const int idx = base + l;
        if (idx < tot) {
            int rem = idx, li = 0;
#pragma unroll
            for (int li2 = 0; li2 < 3; ++li2)
                if (rem >= m[li]) { rem -= m[li]; ++li; }
            const int c = cand[((size_t)(q * NSEG + (li >> 1)) * 2 + (li & 1))
                               * CAP_H + rem];
            double d = chain_dist(ebt + (size_t)c * DIM, xs, ed[c]);
            if (d < bd || (d == bd && c < bc)) { bd = d; bc = c; }
        }
    }
#pragma unroll
    for (int s2 = 0; s2 < NSEG; ++s2) {  // bounded fallback on overflow
        if (segscan[s2]) {
            for (int c = s2 * SEG_CODES + l; c < (s2 + 1) * SEG_CODES; c += 64) {
                double d = chain_dist(ebt + (size_t)c * DIM, xs, ed[c]);
                if (d < bd || (d == bd && c < bc)) { bd = d; bc = c; }
            }
        }
    }
#pragma unroll
    for (int off = 1; off < 64; off <<= 1) {
        double od = __shfl_xor(bd, off, 64);
        int oc = __shfl_xor(bc, off, 64);
        if (od < bd || (od == bd && oc < bc)) { bd = od; bc = oc; }
    }

    float4 e4 = *(const float4*)(ebt + (size_t)bc * DIM + 4 * l);
    *(float4*)(out_q + (size_t)q * DIM + 4 * l) = e4;
    float d0 = e4.x - xf.x, d1 = e4.y - xf.y;
    float d2 = e4.z - xf.z, d3 = e4.w - xf.w;
    double dd = (double)d0 * d0 + (double)d1 * d1 +
                (double)d2 * d2 + (double)d3 * d3;
#pragma unroll
    for (int off = 1; off < 64; off <<= 1) dd += __shfl_xor(dd, off, 64);
    if (l == 0) {
        out_idx[q] = (float)bc;
        dred[w] = dd;
    }
    __syncthreads();
    if (threadIdx.x == 0)
        atomicAdd(pacc + (blockIdx.x & 63),
                  dred[0] + dred[1] + dred[2] + dred[3]);
}

// ---------------------------------------------------------------------------
// finalize: 64 slot reads -> mean -> diff (one wave)
// ---------------------------------------------------------------------------
__global__ void diff_kernel(const double* __restrict__ pacc,
                            float* __restrict__ out_diff) {
    const int t = threadIdx.x;
    double s = pacc[t];
#pragma unroll
    for (int off = 32; off >= 1; off >>= 1) s += __shfl_down(s, off, 64);
    if (t == 0)
        out_diff[0] = (float)(s / (double)OUT_Q_ELEMS);
}

extern "C" void kernel_launch(void* const* d_in, const int* in_sizes, int n_in,
                              void* d_out, int out_size, void* d_ws,
                              size_t ws_size, hipStream_t stream) {
    const float* input = (const float*)d_in[0];  // [8,4096,256] fp32
    const float* embed = (const float*)d_in[1];  // [256,8192]  fp32

    float* out_q    = (float*)d_out;             // quantize
    float* out_diff = out_q + OUT_Q_ELEMS;       // diff scalar
    float* out_idx  = out_diff + 1;              // embed_ind (as float)

    char* p = (char*)d_ws;
    unsigned short* Ec  = (unsigned short*)(p);                 //  4 MB
    unsigned short* Xc  = (unsigned short*)(p + 4194304);       // 16 MB
    float*          ebt = (float*)(p + 20971520);               //  8 MB
    double*         ed  = (double*)(p + 29360128);              // 64 KB
    float*          ef  = (float*)(p + 29425664);               // 32 KB
    int*            cnt2 = (int*)(p + 29458432);                // 512 KB
    double*         pacc = (double*)(p + 29982720);             // 64 slots
    unsigned short* cand = (unsigned short*)(p + 30244864);     //  8.4 MB

    hipLaunchKernelGGL(prep_kernel, dim3(6176), dim3(256), 0, stream,
                       input, embed, cnt2, ed, ef, ebt, Xc, Ec, pacc);
    hipLaunchKernelGGL(mfma_argmin_kernel, dim3((NQ / 128) * NSEG), dim3(512),
                       0, stream, Xc, Ec, ef, cnt2, cand);
    hipLaunchKernelGGL(rescore_kernel, dim3(NQ / 4), dim3(256), 0, stream,
                       input, ebt, ed, cnt2, cand, out_q, out_idx, pacc);
    hipLaunchKernelGGL(diff_kernel, dim3(1), dim3(64), 0, stream,
                       pacc, out_diff);
}